// Round 10
// baseline (129.443 us; speedup 1.0000x reference)
//
#include <hip/hip_runtime.h>
#include <hip/hip_bf16.h>
#include <math.h>

#define NN 4096
#define DD 1024
#define NCLS 128
#define TAU 0.5f
#define EPSV 1e-8f
#define NB_GEMM 256    // 16x16 grid of 256x256 tiles, full square = 1 block/CU
#define NKT 16         // K-tiles (DD / 64)

typedef __bf16 bf16;
typedef __bf16 bf16x8 __attribute__((ext_vector_type(8)));
typedef __bf16 bf16x4 __attribute__((ext_vector_type(4)));
typedef float f32x4 __attribute__((ext_vector_type(4)));

__device__ __forceinline__ void gl2lds16(const void* g, void* l) {
    __builtin_amdgcn_global_load_lds(
        (const __attribute__((address_space(1))) void*)g,
        (__attribute__((address_space(3))) void*)l,
        16, 0, 0);
}

// K1: block 0 = class stats -> per-row first-pos index fpos[i];
//     blocks 1..NN/4 = per-row L2 norm -> normalized bf16 copy, zero rowsum/posv.
__global__ __launch_bounds__(256) void k_prep(const float* __restrict__ X,
                                              const int* __restrict__ y,
                                              bf16* __restrict__ Xn,
                                              float* __restrict__ rsum,
                                              float* __restrict__ posv,
                                              int* __restrict__ cnt,
                                              int* __restrict__ fpos) {
    const int t = threadIdx.x;
    if (blockIdx.x == 0) {
        __shared__ int sc[NCLS], s1[NCLS], s2[NCLS];
        if (t < NCLS) { sc[t] = 0; s1[t] = 0x7fffffff; s2[t] = 0x7fffffff; }
        __syncthreads();
        int yv[16];
#pragma unroll
        for (int k = 0; k < 16; ++k) {
            int i = t + k * 256;
            yv[k] = y[i];
            atomicAdd(&sc[yv[k]], 1);
            atomicMin(&s1[yv[k]], i);
        }
        __syncthreads();
#pragma unroll
        for (int k = 0; k < 16; ++k) {
            int i = t + k * 256;
            if (s1[yv[k]] != i) atomicMin(&s2[yv[k]], i);
        }
        __syncthreads();
#pragma unroll
        for (int k = 0; k < 16; ++k) {
            int i = t + k * 256;
            int c = yv[k];
            fpos[i] = (sc[c] >= 2) ? (s1[c] == i ? s2[c] : s1[c]) : -1;
        }
        if (t < NCLS) cnt[t] = sc[t];
        return;
    }
    const int w = t >> 6, lane = t & 63;
    const int row = (blockIdx.x - 1) * 4 + w;
    const float* xr = X + (size_t)row * DD;
    float4 v[4];
    float ss = 0.f;
#pragma unroll
    for (int c = 0; c < 4; ++c) {
        v[c] = *(const float4*)(xr + c * 256 + lane * 4);
        ss += v[c].x * v[c].x + v[c].y * v[c].y + v[c].z * v[c].z + v[c].w * v[c].w;
    }
#pragma unroll
    for (int m = 1; m < 64; m <<= 1) ss += __shfl_xor(ss, m, 64);
    float rn = 1.f / fmaxf(sqrtf(ss), EPSV);
    if (lane == 0) { rsum[row] = 0.f; posv[row] = 0.f; }
#pragma unroll
    for (int c = 0; c < 4; ++c) {
        bf16x4 o;
        o.x = (bf16)(v[c].x * rn);
        o.y = (bf16)(v[c].y * rn);
        o.z = (bf16)(v[c].z * rn);
        o.w = (bf16)(v[c].w * rn);
        *(bf16x4*)(Xn + (size_t)row * DD + c * 256 + lane * 4) = o;
    }
}

// K2: m201-style 256x256 full-square gram. 1 block/CU, 8 waves (2Mx4N),
// BK=64, 128 KiB LDS (2 dbuf x 2 half x [128][64] x {A,B}).
// Schedule per K-tile: {vmcnt(0) [covered by a full tile of lookahead] ->
// barrier -> issue ALL 8 next-tile gl2lds -> 4 phases of {ds_read, setprio,
// 16 MFMA}}. One barrier + one (pre-covered) vmcnt wait per 64 MFMA.
// Swizzle (rule #21, both-sides-or-neither): LDS dest linear (gl2lds
// requirement); global source pre-swizzled k ^= (row&7) at 16B granules;
// read applies the same XOR -> uniform 8 lanes/16B-slot = conflict-free
// ds_read_b128. NO device-scope fences (round-1 lesson).
__global__ __launch_bounds__(512, 2) void k_gemm(const bf16* __restrict__ Xn,
                                                 const int* __restrict__ y,
                                                 const int* __restrict__ fpos,
                                                 float* __restrict__ rowsum,
                                                 float* __restrict__ posv) {
    __shared__ __align__(16) bf16 As[2][16384];   // 2 x 32 KB
    __shared__ __align__(16) bf16 Bs[2][16384];   // 2 x 32 KB  -> 128 KB total

    // bijective XCD swizzle: 256 = 8 * 32 (each XCD: 2 full row-strips -> A reuse)
    const int id = (blockIdx.x & 7) * 32 + (blockIdx.x >> 3);
    const int rowA0 = (id >> 4) * 256;
    const int rowB0 = (id & 15) * 256;

    const int tid = threadIdx.x;
    const int lane = tid & 63;
    const int w = tid >> 6;              // 0..7
    const int wm = w & 1, wn = w >> 1;   // wave owns 128 rows x 64 cols
    const int lr = lane >> 4, lc = lane & 15;

    f32x4 acc[8][4];
#pragma unroll
    for (int i = 0; i < 8; ++i)
#pragma unroll
        for (int j = 0; j < 4; ++j) acc[i][j] = (f32x4){0.f, 0.f, 0.f, 0.f};

    // ---- staging: thread covers 16B granule G = i*512+tid of each half-tile.
    // granule -> (row = G>>3, slot = G&7); logical k-elems = ((slot^(row&7))*8.
    const int rowoff = tid >> 3;                       // 0..63
    const int kel = ((tid & 7) ^ (rowoff & 7)) * 8;    // inverse-swizzled k
    const bf16* gA = Xn + (size_t)(rowA0 + rowoff) * DD + kel;
    const bf16* gB = Xn + (size_t)(rowB0 + rowoff) * DD + kel;

    auto stage_tile = [&](int buf, int k0) {
#pragma unroll
        for (int h = 0; h < 2; ++h)
#pragma unroll
            for (int i = 0; i < 2; ++i) {
                const size_t go = (size_t)(h * 128 + i * 64) * DD + k0;
                const int de = h * 8192 + (i * 512 + tid) * 8;
                gl2lds16(gA + go, &As[buf][de]);
                gl2lds16(gB + go, &Bs[buf][de]);
            }
    };

    // ---- read-side swizzle: byte ^= ((row&7)<<4); row&7 == lc&7 for all frags
    const int km = (lc & 7) << 4;
    const int koff0 = ((lr * 16) ^ km) >> 1;          // elems, ksub 0
    const int koff1 = ((64 + lr * 16) ^ km) >> 1;     // elems, ksub 1
    const int rB = (wn & 1) * 64;

    // prologue: stage tile 0
    stage_tile(0, 0);

    for (int t = 0; t < NKT; ++t) {
        asm volatile("s_waitcnt vmcnt(0)" ::: "memory");  // pre-covered by 1 tile
        __builtin_amdgcn_s_barrier();
        __builtin_amdgcn_sched_barrier(0);                // pin stage AFTER barrier
        const int c = t & 1;
        if (t + 1 < NKT) stage_tile(c ^ 1, (t + 1) * 64); // full-tile lookahead

        const bf16* Abase = &As[c][wm * 8192];
        const bf16* Bbase = &Bs[c][(wn >> 1) * 8192];
        bf16x8 bq0[4], bq1[4];
#pragma unroll
        for (int nt = 0; nt < 4; ++nt) {
            bq0[nt] = *(const bf16x8*)(Bbase + (rB + nt * 16 + lc) * 64 + koff0);
            bq1[nt] = *(const bf16x8*)(Bbase + (rB + nt * 16 + lc) * 64 + koff1);
        }
#pragma unroll
        for (int p = 0; p < 4; ++p) {
            bf16x8 a00 = *(const bf16x8*)(Abase + ((2 * p) * 16 + lc) * 64 + koff0);
            bf16x8 a01 = *(const bf16x8*)(Abase + ((2 * p) * 16 + lc) * 64 + koff1);
            bf16x8 a10 = *(const bf16x8*)(Abase + ((2 * p + 1) * 16 + lc) * 64 + koff0);
            bf16x8 a11 = *(const bf16x8*)(Abase + ((2 * p + 1) * 16 + lc) * 64 + koff1);
            __builtin_amdgcn_s_setprio(1);
#pragma unroll
            for (int nt = 0; nt < 4; ++nt) {
                acc[2 * p][nt] = __builtin_amdgcn_mfma_f32_16x16x32_bf16(a00, bq0[nt], acc[2 * p][nt], 0, 0, 0);
                acc[2 * p][nt] = __builtin_amdgcn_mfma_f32_16x16x32_bf16(a01, bq1[nt], acc[2 * p][nt], 0, 0, 0);
                acc[2 * p + 1][nt] = __builtin_amdgcn_mfma_f32_16x16x32_bf16(a10, bq0[nt], acc[2 * p + 1][nt], 0, 0, 0);
                acc[2 * p + 1][nt] = __builtin_amdgcn_mfma_f32_16x16x32_bf16(a11, bq1[nt], acc[2 * p + 1][nt], 0, 0, 0);
            }
            __builtin_amdgcn_s_setprio(0);
        }
    }

    // Epilogue (row-side only; R8-verified): S=(c+1)*0.25; same-class masked
    // (diagonal auto-masked); per-row exp-sum over 256 cols; posv at (i,fp(i)).
    int ycol[4], cloc[4];
#pragma unroll
    for (int nt = 0; nt < 4; ++nt) {
        cloc[nt] = wn * 64 + nt * 16 + lc;
        ycol[nt] = y[rowB0 + cloc[nt]];
    }
#pragma unroll
    for (int mt = 0; mt < 8; ++mt) {
#pragma unroll
        for (int rr = 0; rr < 4; ++rr) {
            int rloc = wm * 128 + mt * 16 + lr * 4 + rr;  // C row = (lane>>4)*4+reg
            int rglob = rowA0 + rloc;
            int yrow = y[rglob];
            int fprow = fpos[rglob];
            bool prow = ((unsigned)(fprow - rowB0) < 256u);
            float s = 0.f;
#pragma unroll
            for (int nt = 0; nt < 4; ++nt) {
                float Sv = (acc[mt][nt][rr] + 1.f) * (0.5f * TAU);
                if (prow && rowB0 + cloc[nt] == fprow) posv[rglob] = Sv;
                s += (ycol[nt] != yrow) ? __expf(Sv) : 0.f;
            }
            s += __shfl_xor(s, 1, 16);
            s += __shfl_xor(s, 2, 16);
            s += __shfl_xor(s, 4, 16);
            s += __shfl_xor(s, 8, 16);
            if (lc == 0) atomicAdd(&rowsum[rglob], s);
        }
    }
}

// K3: single block; lse_i = log(rowsum_i + exp(pv_i) + (N-2+cnt)); out = mean(lse - pv)
__global__ __launch_bounds__(1024) void k_finalize(const float* __restrict__ rowsum,
                                                   const float* __restrict__ posv,
                                                   const int* __restrict__ y,
                                                   const int* __restrict__ cnt,
                                                   float* __restrict__ out) {
    int t = threadIdx.x;
    float acc = 0.f;
#pragma unroll
    for (int k = 0; k < 4; ++k) {
        int i = t + k * 1024;
        float pv = posv[i];
        float tot = rowsum[i] + __expf(pv) + (float)(NN - 2 + cnt[y[i]]);
        acc += logf(tot) - pv;
    }
#pragma unroll
    for (int m = 1; m < 64; m <<= 1) acc += __shfl_xor(acc, m, 64);
    __shared__ float wsum[16];
    int w = t >> 6, lane = t & 63;
    if (lane == 0) wsum[w] = acc;
    __syncthreads();
    if (t == 0) {
        float s = 0.f;
#pragma unroll
        for (int q = 0; q < 16; ++q) s += wsum[q];
        *out = s / (float)NN;
    }
}

extern "C" void kernel_launch(void* const* d_in, const int* in_sizes, int n_in,
                              void* d_out, int out_size, void* d_ws, size_t ws_size,
                              hipStream_t stream) {
    const float* X = (const float*)d_in[0];
    const int* y = (const int*)d_in[1];
    float* out = (float*)d_out;

    char* ws = (char*)d_ws;
    bf16* Xn    = (bf16*)ws;                                   // 8 MB
    float* rsum = (float*)(ws + 8 * 1024 * 1024);              // 16 KB
    float* posv = (float*)(ws + 8 * 1024 * 1024 + 16 * 1024);  // 16 KB
    int* cnt    = (int*)(ws + 8 * 1024 * 1024 + 32 * 1024);    // 512 B
    int* fpos   = (int*)(ws + 8 * 1024 * 1024 + 36 * 1024);    // 16 KB

    k_prep<<<dim3(NN / 4 + 1), 256, 0, stream>>>(X, y, Xn, rsum, posv, cnt, fpos);
    k_gemm<<<dim3(NB_GEMM), 512, 0, stream>>>(Xn, y, fpos, rsum, posv);
    k_finalize<<<dim3(1), 1024, 0, stream>>>(rsum, posv, y, cnt, out);
}

// Round 11
// 126.137 us; speedup vs baseline: 1.0262x; 1.0262x over previous
//
#include <hip/hip_runtime.h>
#include <hip/hip_bf16.h>
#include <math.h>

#define NN 4096
#define DD 1024
#define NCLS 128
#define TAU 0.5f
#define EPSV 1e-8f
#define NB_GEMM 256    // 16x16 grid of 256x256 tiles, full square = 1 block/CU
#define NKT 16         // K-tiles (DD / 64)

typedef __bf16 bf16;
typedef __bf16 bf16x8 __attribute__((ext_vector_type(8)));
typedef __bf16 bf16x4 __attribute__((ext_vector_type(4)));
typedef float f32x4 __attribute__((ext_vector_type(4)));

__device__ __forceinline__ void gl2lds16(const void* g, void* l) {
    __builtin_amdgcn_global_load_lds(
        (const __attribute__((address_space(1))) void*)g,
        (__attribute__((address_space(3))) void*)l,
        16, 0, 0);
}

// K1: block 0 = class stats -> per-row first-pos index fpos[i];
//     blocks 1..NN/4 = per-row L2 norm -> normalized bf16 copy, zero rowsum/posv.
__global__ __launch_bounds__(256) void k_prep(const float* __restrict__ X,
                                              const int* __restrict__ y,
                                              bf16* __restrict__ Xn,
                                              float* __restrict__ rsum,
                                              float* __restrict__ posv,
                                              int* __restrict__ cnt,
                                              int* __restrict__ fpos) {
    const int t = threadIdx.x;
    if (blockIdx.x == 0) {
        __shared__ int sc[NCLS], s1[NCLS], s2[NCLS];
        if (t < NCLS) { sc[t] = 0; s1[t] = 0x7fffffff; s2[t] = 0x7fffffff; }
        __syncthreads();
        int yv[16];
#pragma unroll
        for (int k = 0; k < 16; ++k) {
            int i = t + k * 256;
            yv[k] = y[i];
            atomicAdd(&sc[yv[k]], 1);
            atomicMin(&s1[yv[k]], i);
        }
        __syncthreads();
#pragma unroll
        for (int k = 0; k < 16; ++k) {
            int i = t + k * 256;
            if (s1[yv[k]] != i) atomicMin(&s2[yv[k]], i);
        }
        __syncthreads();
#pragma unroll
        for (int k = 0; k < 16; ++k) {
            int i = t + k * 256;
            int c = yv[k];
            fpos[i] = (sc[c] >= 2) ? (s1[c] == i ? s2[c] : s1[c]) : -1;
        }
        if (t < NCLS) cnt[t] = sc[t];
        return;
    }
    const int w = t >> 6, lane = t & 63;
    const int row = (blockIdx.x - 1) * 4 + w;
    const float* xr = X + (size_t)row * DD;
    float4 v[4];
    float ss = 0.f;
#pragma unroll
    for (int c = 0; c < 4; ++c) {
        v[c] = *(const float4*)(xr + c * 256 + lane * 4);
        ss += v[c].x * v[c].x + v[c].y * v[c].y + v[c].z * v[c].z + v[c].w * v[c].w;
    }
#pragma unroll
    for (int m = 1; m < 64; m <<= 1) ss += __shfl_xor(ss, m, 64);
    float rn = 1.f / fmaxf(sqrtf(ss), EPSV);
    if (lane == 0) { rsum[row] = 0.f; posv[row] = 0.f; }
#pragma unroll
    for (int c = 0; c < 4; ++c) {
        bf16x4 o;
        o.x = (bf16)(v[c].x * rn);
        o.y = (bf16)(v[c].y * rn);
        o.z = (bf16)(v[c].z * rn);
        o.w = (bf16)(v[c].w * rn);
        *(bf16x4*)(Xn + (size_t)row * DD + c * 256 + lane * 4) = o;
    }
}

// K2: 256x256 full-square gram, m201 8-phase-style schedule on R10's verified
// addressing. Per K-tile: 4 phases of {ds_read subtile || stage 1 half-tile
// (2 gl2lds) -> lgkmcnt(0) -> setprio(1) 16 MFMA setprio(0) -> barrier}.
// ONE vmem wait per tile: vmcnt(2) at phase 0 (tile t's 8 loads = oldest;
// only the 2 just-issued t+1 loads stay in flight). Never drain to 0 except
// the peeled last tile (m218: counted-vs-drain0 = the lever; m196: fine
// interleave required). Swizzle both-sides (rule #21): linear LDS dest,
// global source k^=(row&7) at 16B granules, read XORs the same mask.
// NO device-scope fences (round-1 lesson).
__global__ __launch_bounds__(512, 2) void k_gemm(const bf16* __restrict__ Xn,
                                                 const int* __restrict__ y,
                                                 const int* __restrict__ fpos,
                                                 float* __restrict__ rowsum,
                                                 float* __restrict__ posv) {
    __shared__ __align__(16) bf16 As[2][16384];   // 2 x 32 KB
    __shared__ __align__(16) bf16 Bs[2][16384];   // 2 x 32 KB  -> 128 KB total

    // bijective XCD swizzle: 256 = 8 * 32
    const int id = (blockIdx.x & 7) * 32 + (blockIdx.x >> 3);
    const int rowA0 = (id >> 4) * 256;
    const int rowB0 = (id & 15) * 256;

    const int tid = threadIdx.x;
    const int lane = tid & 63;
    const int w = tid >> 6;              // 0..7
    const int wm = w & 1, wn = w >> 1;   // wave owns 128 rows x 64 cols
    const int lr = lane >> 4, lc = lane & 15;

    f32x4 acc[8][4];
#pragma unroll
    for (int i = 0; i < 8; ++i)
#pragma unroll
        for (int j = 0; j < 4; ++j) acc[i][j] = (f32x4){0.f, 0.f, 0.f, 0.f};

    // staging: thread covers 16B granule; row = G>>3, slot = G&7,
    // source k pre-swizzled: kel = ((slot ^ (row&7)) * 8.
    const int rowoff = tid >> 3;                       // 0..63
    const int kel = ((tid & 7) ^ (rowoff & 7)) * 8;
    const bf16* gA = Xn + (size_t)(rowA0 + rowoff) * DD + kel;
    const bf16* gB = Xn + (size_t)(rowB0 + rowoff) * DD + kel;

    // half-tile pair p (p=0..3): rows (p>>1)*128 + (p&1)*64, A and B together.
    auto stage_pair = [&](int buf, int p, int k0) {
        const int h = p >> 1, i = p & 1;
        const size_t go = (size_t)(h * 128 + i * 64) * DD + k0;
        const int de = h * 8192 + (i * 512 + tid) * 8;
        gl2lds16(gA + go, &As[buf][de]);
        gl2lds16(gB + go, &Bs[buf][de]);
    };

    // read-side swizzle (R10-verified): byte ^= ((row&7)<<4)
    const int km = (lc & 7) << 4;
    const int koff0 = ((lr * 16) ^ km) >> 1;          // elems, ksub 0
    const int koff1 = ((64 + lr * 16) ^ km) >> 1;     // elems, ksub 1
    const int rB = (wn & 1) * 64;

    bf16x8 aA[4][2];     // current qm's A-frags [mt][ksub]
    bf16x8 bq[2][2][2];  // B-frags [qn][ntl][ksub], live across phases

    auto loadA = [&](int c, int qm) {
        const bf16* Abase = &As[c][wm * 8192];
#pragma unroll
        for (int mt = 0; mt < 4; ++mt) {
            const bf16* rp = Abase + ((qm * 4 + mt) * 16 + lc) * 64;
            aA[mt][0] = *(const bf16x8*)(rp + koff0);
            aA[mt][1] = *(const bf16x8*)(rp + koff1);
        }
    };
    auto loadB = [&](int c, int qn) {
        const bf16* Bbase = &Bs[c][(wn >> 1) * 8192];
#pragma unroll
        for (int ntl = 0; ntl < 2; ++ntl) {
            const bf16* rp = Bbase + (rB + (qn * 2 + ntl) * 16 + lc) * 64;
            bq[qn][ntl][0] = *(const bf16x8*)(rp + koff0);
            bq[qn][ntl][1] = *(const bf16x8*)(rp + koff1);
        }
    };
    auto mfma16 = [&](int qm, int qn) {
        __builtin_amdgcn_s_setprio(1);
#pragma unroll
        for (int mt = 0; mt < 4; ++mt)
#pragma unroll
            for (int ntl = 0; ntl < 2; ++ntl) {
                acc[qm * 4 + mt][qn * 2 + ntl] = __builtin_amdgcn_mfma_f32_16x16x32_bf16(
                    aA[mt][0], bq[qn][ntl][0], acc[qm * 4 + mt][qn * 2 + ntl], 0, 0, 0);
                acc[qm * 4 + mt][qn * 2 + ntl] = __builtin_amdgcn_mfma_f32_16x16x32_bf16(
                    aA[mt][1], bq[qn][ntl][1], acc[qm * 4 + mt][qn * 2 + ntl], 0, 0, 0);
            }
        __builtin_amdgcn_s_setprio(0);
    };

    auto ktile = [&](int c, int knext, bool stage_on, bool lastWait) {
        // ---- phase 0: stage p0 | wait tile-c landed | A[0]+B[0] reads | 16 MFMA
        if (stage_on) stage_pair(c ^ 1, 0, knext);
        if (lastWait) asm volatile("s_waitcnt vmcnt(0)" ::: "memory");
        else          asm volatile("s_waitcnt vmcnt(2)" ::: "memory");
        __builtin_amdgcn_s_barrier();
        loadA(c, 0);
        loadB(c, 0);
        asm volatile("s_waitcnt lgkmcnt(0)" ::: "memory");
        mfma16(0, 0);
        __builtin_amdgcn_s_barrier();
        // ---- phase 1: B[1] reads | stage p1 | 16 MFMA
        loadB(c, 1);
        if (stage_on) stage_pair(c ^ 1, 1, knext);
        asm volatile("s_waitcnt lgkmcnt(0)" ::: "memory");
        mfma16(0, 1);
        __builtin_amdgcn_s_barrier();
        // ---- phase 2: A[1] reads | stage p2 | 16 MFMA
        loadA(c, 1);
        if (stage_on) stage_pair(c ^ 1, 2, knext);
        asm volatile("s_waitcnt lgkmcnt(0)" ::: "memory");
        mfma16(1, 0);
        __builtin_amdgcn_s_barrier();
        // ---- phase 3: stage p3 | 16 MFMA (regs already live)
        if (stage_on) stage_pair(c ^ 1, 3, knext);
        mfma16(1, 1);
        __builtin_amdgcn_s_barrier();
    };

    // prologue: stage tile 0 (8 loads)
#pragma unroll
    for (int p = 0; p < 4; ++p) stage_pair(0, p, 0);

#pragma unroll 2
    for (int t = 0; t < NKT - 1; ++t)
        ktile(t & 1, (t + 1) * 64, true, false);
    ktile((NKT - 1) & 1, 0, false, true);   // peeled last tile: full drain OK

    // Epilogue (row-side only; R8/R10-verified): S=(c+1)*0.25; same-class
    // masked (diagonal auto-masked); per-row exp-sum; posv at (i,fp(i)).
    int ycol[4], cloc[4];
#pragma unroll
    for (int nt = 0; nt < 4; ++nt) {
        cloc[nt] = wn * 64 + nt * 16 + lc;
        ycol[nt] = y[rowB0 + cloc[nt]];
    }
#pragma unroll
    for (int mt = 0; mt < 8; ++mt) {
#pragma unroll
        for (int rr = 0; rr < 4; ++rr) {
            int rloc = wm * 128 + mt * 16 + lr * 4 + rr;  // C row = (lane>>4)*4+reg
            int rglob = rowA0 + rloc;
            int yrow = y[rglob];
            int fprow = fpos[rglob];
            bool prow = ((unsigned)(fprow - rowB0) < 256u);
            float s = 0.f;
#pragma unroll
            for (int nt = 0; nt < 4; ++nt) {
                float Sv = (acc[mt][nt][rr] + 1.f) * (0.5f * TAU);
                if (prow && rowB0 + cloc[nt] == fprow) posv[rglob] = Sv;
                s += (ycol[nt] != yrow) ? __expf(Sv) : 0.f;
            }
            s += __shfl_xor(s, 1, 16);
            s += __shfl_xor(s, 2, 16);
            s += __shfl_xor(s, 4, 16);
            s += __shfl_xor(s, 8, 16);
            if (lc == 0) atomicAdd(&rowsum[rglob], s);
        }
    }
}

// K3: single block; lse_i = log(rowsum_i + exp(pv_i) + (N-2+cnt)); out = mean(lse - pv)
__global__ __launch_bounds__(1024) void k_finalize(const float* __restrict__ rowsum,
                                                   const float* __restrict__ posv,
                                                   const int* __restrict__ y,
                                                   const int* __restrict__ cnt,
                                                   float* __restrict__ out) {
    int t = threadIdx.x;
    float acc = 0.f;
#pragma unroll
    for (int k = 0; k < 4; ++k) {
        int i = t + k * 1024;
        float pv = posv[i];
        float tot = rowsum[i] + __expf(pv) + (float)(NN - 2 + cnt[y[i]]);
        acc += logf(tot) - pv;
    }
#pragma unroll
    for (int m = 1; m < 64; m <<= 1) acc += __shfl_xor(acc, m, 64);
    __shared__ float wsum[16];
    int w = t >> 6, lane = t & 63;
    if (lane == 0) wsum[w] = acc;
    __syncthreads();
    if (t == 0) {
        float s = 0.f;
#pragma unroll
        for (int q = 0; q < 16; ++q) s += wsum[q];
        *out = s / (float)NN;
    }
}

extern "C" void kernel_launch(void* const* d_in, const int* in_sizes, int n_in,
                              void* d_out, int out_size, void* d_ws, size_t ws_size,
                              hipStream_t stream) {
    const float* X = (const float*)d_in[0];
    const int* y = (const int*)d_in[1];
    float* out = (float*)d_out;

    char* ws = (char*)d_ws;
    bf16* Xn    = (bf16*)ws;                                   // 8 MB
    float* rsum = (float*)(ws + 8 * 1024 * 1024);              // 16 KB
    float* posv = (float*)(ws + 8 * 1024 * 1024 + 16 * 1024);  // 16 KB
    int* cnt    = (int*)(ws + 8 * 1024 * 1024 + 32 * 1024);    // 512 B
    int* fpos   = (int*)(ws + 8 * 1024 * 1024 + 36 * 1024);    // 16 KB

    k_prep<<<dim3(NN / 4 + 1), 256, 0, stream>>>(X, y, Xn, rsum, posv, cnt, fpos);
    k_gemm<<<dim3(NB_GEMM), 512, 0, stream>>>(Xn, y, fpos, rsum, posv);
    k_finalize<<<dim3(1), 1024, 0, stream>>>(rsum, posv, y, cnt, out);
}